// Round 1
// baseline (461.424 us; speedup 1.0000x reference)
//
#include <hip/hip_runtime.h>

#define NN 100000
#define NE 1600000
#define DD 128            // IN_DIM == HID == 128
#define OUT_HALF 6400000  // NN * 64
#define CAP 64            // slots per node (max degree on this fixed graph ~42)

// ---- binned-build parameters ----
#define NB 1024           // destination buckets
#define NPB 98            // nodes per bucket (1024*98 = 100352 >= NN)
#define BCAP 2048         // record capacity per bucket (E[n]=1563, +12 sigma)
#define BSTRIDE 64        // ints between bucket counters (256B apart -> slice spread)

typedef unsigned int uint_t;

// round-to-nearest-even fp32 -> bf16 (as ushort)
__device__ __forceinline__ unsigned short f2bf(float f) {
    uint_t u = __float_as_uint(f);
    u = (u + 0x7fffu + ((u >> 16) & 1u)) >> 16;
    return (unsigned short)u;
}
__device__ __forceinline__ float bf_lo(uint_t u) { return __uint_as_float(u << 16); }
__device__ __forceinline__ float bf_hi(uint_t u) { return __uint_as_float(u & 0xffff0000u); }

#define EW_SCALE 32767.0f
#define EW_INV (1.0f / 32767.0f)

// ---------------- build: 2-phase binned capacity-CSR ------------------------
// Phase 1: append (payload, col) records into 1024 destination-range buckets.
// Appends get consecutive positions -> write frontier is ~1 line/bucket ->
// full-line writebacks (vs 96MB of partial-line scatter in the 1-pass build).
// Phase 2: one block per bucket; LDS-packed counter gives slot pos + sum(q)
// in ONE ds_add; slot writes land in a 25KB L2-resident window. Also emits
// cnt[] and dinv[] (replaces k_initcnt + k_deg).

__global__ void k_zero(int* __restrict__ bcnt) {
    int i = blockIdx.x * blockDim.x + threadIdx.x;
    if (i < NB) bcnt[i * BSTRIDE] = 0;
}

__global__ void k_bin(const int* __restrict__ row, const int* __restrict__ col,
                      const float* __restrict__ ew, int* __restrict__ bcnt,
                      uint2* __restrict__ bins) {
    int e = blockIdx.x * blockDim.x + threadIdx.x;
    if (e >= NE) return;
    uint_t c = (uint_t)col[e];
    uint_t r = (uint_t)row[e];
    uint_t q = (uint_t)__float2int_rn(ew[e] * EW_SCALE);  // ew in [0,1)
    uint_t b = c / NPB;                                   // magic-mul div
    int pos = atomicAdd(&bcnt[b * BSTRIDE], 1) & (BCAP - 1);  // clamp defensive
    bins[b * BCAP + pos] = make_uint2((r << 15) | q, c);
}

__launch_bounds__(256)
__global__ void k_scatter(const int* __restrict__ bcnt, const uint2* __restrict__ bins,
                          int* __restrict__ cnt, uint_t* __restrict__ slots,
                          float* __restrict__ dinv) {
    // combo[lc]: bits 22..31 = edge count, bits 0..21 = sum of q (q<=32767,
    // deg<=42 -> qsum < 1.4M < 2^21, no field overflow on this graph).
    __shared__ int combo[NPB];
    const int b = blockIdx.x;
    const int tid = threadIdx.x;
    if (tid < NPB) combo[tid] = 0;
    __syncthreads();
    int n = bcnt[b * BSTRIDE];
    n = (n < BCAP) ? n : BCAP;
    const int base = b * NPB;
    const uint2* seg = bins + (size_t)b * BCAP;
    for (int i = tid; i < n; i += 256) {
        uint2 rec = seg[i];
        int lc = (int)rec.y - base;
        uint_t w = rec.x & 0x7fffu;
        uint_t old = (uint_t)atomicAdd(&combo[lc], (int)((1u << 22) | w));
        uint_t pos = old >> 22;
        if (pos < CAP) slots[rec.y * CAP + pos] = rec.x;
    }
    __syncthreads();
    if (tid < NPB) {
        int node = base + tid;
        if (node < NN) {
            uint_t v = (uint_t)combo[tid];
            int c = (int)(v >> 22);
            cnt[node] = (c < CAP) ? c : CAP;
            dinv[node] = rsqrtf(1.0f + (float)(v & 0x3fffffu) * EW_INV);
        }
    }
}

// ---------------- gather: one wave per destination node ----------------
// acc[c] = y[c] + sum_e ew_e * y[row_e]          (y rows are dinv-prescaled)
// RELU path (layer1): store y1 = dinv[c]*relu(dinv[c]*acc + b)   (bf16)
// else    (layer2): store g = dinv[c]*acc                         (fp32)

template <bool RELU, bool OUT_BF16>
__launch_bounds__(256)
__global__ void k_gather(const uint_t* __restrict__ src, const int* __restrict__ cnt,
                         const uint_t* __restrict__ slots, const float* __restrict__ dinv,
                         const float* __restrict__ bias, void* __restrict__ dst) {
    int wid = (blockIdx.x * blockDim.x + threadIdx.x) >> 6;  // node id
    int lane = threadIdx.x & 63;
    if (wid >= NN) return;
    float di = dinv[wid];
    uint_t u = src[wid * 64 + lane];
    float accx = bf_lo(u);
    float accy = bf_hi(u);
    int end = __builtin_amdgcn_readfirstlane(cnt[wid]);
    const uint_t* seg = slots + wid * CAP;
    for (int jj = 0; jj < end; jj += 8) {
        uint_t rp[8];
#pragma unroll
        for (int q = 0; q < 8; ++q) {
            int idx = (jj + q < end) ? (jj + q) : (end - 1);  // clamp: valid slot
            rp[q] = seg[idx];
        }
        uint_t sv[8];
#pragma unroll
        for (int q = 0; q < 8; ++q) {
            sv[q] = src[(rp[q] >> 15) * 64 + lane];
        }
#pragma unroll
        for (int q = 0; q < 8; ++q) {
            float p = (jj + q < end) ? (float)(rp[q] & 0x7fffu) * EW_INV : 0.0f;
            accx = fmaf(p, bf_lo(sv[q]), accx);
            accy = fmaf(p, bf_hi(sv[q]), accy);
        }
    }
    accx *= di;
    accy *= di;
    if (RELU) {
        float2 b = ((const float2*)bias)[lane];
        accx = fmaxf(accx + b.x, 0.0f) * di;  // prescale for next layer
        accy = fmaxf(accy + b.y, 0.0f) * di;
    }
    if (OUT_BF16) {
        ((uint_t*)dst)[wid * 64 + lane] =
            (uint_t)f2bf(accx) | ((uint_t)f2bf(accy) << 16);
    } else {
        ((float2*)dst)[wid * 64 + lane] = make_float2(accx, accy);
    }
}

// ------- GEMM: Y[n,:] = dinv[n] * (X[n,:] @ W), bf16 out (dinv-prescaled) -----
// 32-node x 128-col tile. X staged in LDS as float4 k-groups, pitch 33 float4s
// (odd 16B stride -> conflict-free b128 writes, no transpose). Per k-group:
// 8 ds_read_b128 (4 W rows + 4 x float4s, broadcast) feed 64 FMAs/thread.

__launch_bounds__(256)
__global__ void k_gemm_h0(const float* __restrict__ X, const float* __restrict__ W,
                          const float* __restrict__ dinv, uint_t* __restrict__ Y) {
    __shared__ float Ws[64 * 128];      // 32 KB, one k-half of W
    __shared__ float4 xs4[32 * 33];     // 16.9 KB: xs4[kg*33+n] = X[n][4kg..4kg+3]
    const int tid = threadIdx.x;
    const int node0 = blockIdx.x * 32;

    {
        const float4* X4 = (const float4*)X;
        for (int i = tid; i < 32 * 32; i += 256) {
            int n = i >> 5, kg = i & 31;   // coalesced global, conflict-free LDS
            xs4[kg * 33 + n] = X4[(node0 + n) * 32 + kg];
        }
    }

    const int jg = tid & 31, ng = tid >> 5;
    const int j0 = jg * 4, n0 = ng * 4;
    float acc[4][4];
#pragma unroll
    for (int a = 0; a < 4; ++a)
#pragma unroll
        for (int b = 0; b < 4; ++b) acc[a][b] = 0.0f;

    for (int half = 0; half < 2; ++half) {
        __syncthreads();  // xs4 ready / Ws no longer in use
        const float4* Wsrc = (const float4*)(W + half * 64 * 128);
        float4* Wd = (float4*)Ws;
        for (int i = tid; i < 64 * 32; i += 256) Wd[i] = Wsrc[i];
        __syncthreads();
#pragma unroll 4
        for (int kk4 = 0; kk4 < 16; ++kk4) {
            float4 wk[4], xa[4];
#pragma unroll
            for (int c = 0; c < 4; ++c)
                wk[c] = *(const float4*)&Ws[(kk4 * 4 + c) * 128 + j0];
#pragma unroll
            for (int a = 0; a < 4; ++a)
                xa[a] = xs4[(half * 16 + kk4) * 33 + n0 + a];
            float wv[4][4], xv[4][4];
#pragma unroll
            for (int c = 0; c < 4; ++c) {
                wv[c][0] = wk[c].x; wv[c][1] = wk[c].y;
                wv[c][2] = wk[c].z; wv[c][3] = wk[c].w;
            }
#pragma unroll
            for (int a = 0; a < 4; ++a) {
                xv[a][0] = xa[a].x; xv[a][1] = xa[a].y;
                xv[a][2] = xa[a].z; xv[a][3] = xa[a].w;
            }
#pragma unroll
            for (int c = 0; c < 4; ++c)
#pragma unroll
                for (int a = 0; a < 4; ++a)
#pragma unroll
                    for (int b = 0; b < 4; ++b)
                        acc[a][b] = fmaf(xv[a][c], wv[c][b], acc[a][b]);
        }
    }

#pragma unroll
    for (int a = 0; a < 4; ++a) {
        int node = node0 + n0 + a;
        float di = dinv[node];
        uint2 o;
        o.x = (uint_t)f2bf(acc[a][0] * di) | ((uint_t)f2bf(acc[a][1] * di) << 16);
        o.y = (uint_t)f2bf(acc[a][2] * di) | ((uint_t)f2bf(acc[a][3] * di) << 16);
        *(uint2*)&Y[node * 64 + (j0 >> 1)] = o;
    }
}

// ---------------- final GEMM: [mu|lv] = G @ [Wmu|Wlv] + [bmu|blv] -> d_out ----

__launch_bounds__(256)
__global__ void k_gemm_out(const float* __restrict__ G, const float* __restrict__ Wmu,
                           const float* __restrict__ Wlv, const float* __restrict__ bmu,
                           const float* __restrict__ blv, float* __restrict__ out) {
    __shared__ float Ws[64 * 128];
    __shared__ float4 xs4[32 * 33];
    const int tid = threadIdx.x;
    const int node0 = blockIdx.x * 32;

    {
        const float4* G4 = (const float4*)G;
        for (int i = tid; i < 32 * 32; i += 256) {
            int n = i >> 5, kg = i & 31;
            xs4[kg * 33 + n] = G4[(node0 + n) * 32 + kg];
        }
    }

    const int jg = tid & 31, ng = tid >> 5;
    const int j0 = jg * 4, n0 = ng * 4;
    float acc[4][4];
#pragma unroll
    for (int a = 0; a < 4; ++a)
#pragma unroll
        for (int b = 0; b < 4; ++b) acc[a][b] = 0.0f;

    for (int half = 0; half < 2; ++half) {
        __syncthreads();
        for (int i = tid; i < 64 * 32; i += 256) {
            int kk = i >> 5;
            int j = (i & 31) * 4;
            int k = half * 64 + kk;
            float4 v = (j < 64) ? *(const float4*)(Wmu + k * 64 + j)
                                : *(const float4*)(Wlv + k * 64 + (j - 64));
            ((float4*)Ws)[i] = v;
        }
        __syncthreads();
#pragma unroll 4
        for (int kk4 = 0; kk4 < 16; ++kk4) {
            float4 wk[4], xa[4];
#pragma unroll
            for (int c = 0; c < 4; ++c)
                wk[c] = *(const float4*)&Ws[(kk4 * 4 + c) * 128 + j0];
#pragma unroll
            for (int a = 0; a < 4; ++a)
                xa[a] = xs4[(half * 16 + kk4) * 33 + n0 + a];
            float wv[4][4], xv[4][4];
#pragma unroll
            for (int c = 0; c < 4; ++c) {
                wv[c][0] = wk[c].x; wv[c][1] = wk[c].y;
                wv[c][2] = wk[c].z; wv[c][3] = wk[c].w;
            }
#pragma unroll
            for (int a = 0; a < 4; ++a) {
                xv[a][0] = xa[a].x; xv[a][1] = xa[a].y;
                xv[a][2] = xa[a].z; xv[a][3] = xa[a].w;
            }
#pragma unroll
            for (int c = 0; c < 4; ++c)
#pragma unroll
                for (int a = 0; a < 4; ++a)
#pragma unroll
                    for (int b = 0; b < 4; ++b)
                        acc[a][b] = fmaf(xv[a][c], wv[c][b], acc[a][b]);
        }
    }

    float4 bb = (j0 < 64) ? *(const float4*)&bmu[j0] : *(const float4*)&blv[j0 - 64];
#pragma unroll
    for (int a = 0; a < 4; ++a) {
        int node = node0 + n0 + a;
        float4 v = make_float4(acc[a][0] + bb.x, acc[a][1] + bb.y,
                               acc[a][2] + bb.z, acc[a][3] + bb.w);
        if (j0 < 64)
            *(float4*)&out[node * 64 + j0] = v;
        else
            *(float4*)&out[OUT_HALF + node * 64 + (j0 - 64)] = v;
    }
}

// ---------------- launch ----------------

extern "C" void kernel_launch(void* const* d_in, const int* in_sizes, int n_in,
                              void* d_out, int out_size, void* d_ws, size_t ws_size,
                              hipStream_t stream) {
    const float* x   = (const float*)d_in[0];
    const int*   ei  = (const int*)d_in[1];   // [2, NE] int32 on device
    const float* ew  = (const float*)d_in[2];
    const float* W1  = (const float*)d_in[3];
    const float* b1  = (const float*)d_in[4];
    const float* Wmu = (const float*)d_in[5];
    const float* bmu = (const float*)d_in[6];
    const float* Wlv = (const float*)d_in[7];
    const float* blv = (const float*)d_in[8];
    const int* rowi = ei;        // sources
    const int* coli = ei + NE;   // destinations
    float* out = (float*)d_out;

    // workspace layout (4B elements). poolA holds y0 (bf16, 25.6MB) then is
    // overwritten by g (fp32, 51.2MB) during gather2 — y0 is dead by then.
    // During the BUILD phase (before k_gemm_h0 writes y0), poolA's first 17MB
    // is reused as bins (16.8MB) + bcnt (256KB) — both dead after k_scatter.
    int*    cnt   = (int*)d_ws;                  // NN ints, pad 100352
    float*  dinv  = (float*)(cnt + 100352);      // NN floats, pad 100352
    uint_t* slots = (uint_t*)(dinv + 100352);    // NN*CAP uints (25.6 MB)
    float*  poolA = (float*)(slots + NN * CAP);  // NN*128 floats (51.2 MB)
    uint_t* y0    = (uint_t*)poolA;              // NN*64 uints (bf16x2)
    float*  g     = poolA;                       // NN*128 floats
    uint_t* y1    = (uint_t*)(poolA + NN * DD);  // NN*64 uints (25.6 MB)
    uint2*  bins  = (uint2*)poolA;               // NB*BCAP uint2 (16.8 MB)
    int*    bcnt  = (int*)(poolA + NB * BCAP * 2);  // NB*BSTRIDE ints (256 KB)

    const int B = 256;
    // binned build: bucket-append (coalesced writebacks) -> per-bucket scatter
    k_zero<<<(NB + B - 1) / B, B, 0, stream>>>(bcnt);
    k_bin<<<(NE + B - 1) / B, B, 0, stream>>>(rowi, coli, ew, bcnt, bins);
    // per-bucket: slot placement via single packed LDS atomic; emits cnt+dinv
    k_scatter<<<NB, B, 0, stream>>>(bcnt, bins, cnt, slots, dinv);
    // layer 1: y0 = dinv .* (x @ W1) -> bf16
    k_gemm_h0<<<NN / 32, B, 0, stream>>>(x, W1, dinv, y0);
    // y1 = dinv .* relu(dinv .* (y0[c] + sum ew*y0[r]) + b1) -> bf16
    k_gather<true, true><<<(NN * 64 + B - 1) / B, B, 0, stream>>>(
        y0, cnt, slots, dinv, b1, y1);
    // g = dinv .* (y1[c] + sum ew*y1[r]) -> fp32 (overwrites y0)
    k_gather<false, false><<<(NN * 64 + B - 1) / B, B, 0, stream>>>(
        y1, cnt, slots, dinv, b1, g);
    // [mu|logvar] = g @ [Wmu|Wlv] + bias -> d_out
    k_gemm_out<<<NN / 32, B, 0, stream>>>(g, Wmu, Wlv, bmu, blv, out);
}

// Round 2
// 397.396 us; speedup vs baseline: 1.1611x; 1.1611x over previous
//
#include <hip/hip_runtime.h>

#define NN 100000
#define NE 1600000
#define DD 128            // IN_DIM == HID == 128
#define OUT_HALF 6400000  // NN * 64
#define CAP 64            // slots per node (max degree on this fixed graph ~42)

// ---- binned-build parameters ----
#define NB 256            // coarse destination buckets (== k_bin block size)
#define NPB 391           // nodes per bucket (256*391 = 100096 >= NN)
#define BCAP 8192         // record capacity per bucket (E[n]=6250, +24 sigma)
#define BSTRIDE 64        // ints between bucket counters (256B apart)
#define CHUNK 6144        // edges per k_bin block (48KB LDS staging)
#define CPT 24            // CHUNK / 256

typedef unsigned int uint_t;

// round-to-nearest-even fp32 -> bf16 (as ushort)
__device__ __forceinline__ unsigned short f2bf(float f) {
    uint_t u = __float_as_uint(f);
    u = (u + 0x7fffu + ((u >> 16) & 1u)) >> 16;
    return (unsigned short)u;
}
__device__ __forceinline__ float bf_lo(uint_t u) { return __uint_as_float(u << 16); }
__device__ __forceinline__ float bf_hi(uint_t u) { return __uint_as_float(u & 0xffff0000u); }

#define EW_SCALE 32767.0f
#define EW_INV (1.0f / 32767.0f)

// ---------------- build: block-local counting sort -> binned CSR -------------
// R1 lesson: global bucket-appends do NOT write-combine — consecutive slots are
// claimed by different CUs on non-coherent XCD L2s, so every 8B record writes
// back its own 64B line (90MB observed). Fix: create contiguity INSIDE a block.
// Each block sorts 6144 edges by coarse bucket in LDS, takes ONE global cursor
// atomic per (block,bucket), and streams each run out contiguously from one CU
// -> full-line writebacks (~17MB total), 67K global atomics instead of 1.6M.

__global__ void k_zero(int* __restrict__ bcnt) {
    int i = blockIdx.x * blockDim.x + threadIdx.x;
    if (i < NB * BSTRIDE) bcnt[i] = 0;
}

__launch_bounds__(256)
__global__ void k_bin(const int* __restrict__ row, const int* __restrict__ col,
                      const float* __restrict__ ew, int* __restrict__ bcnt,
                      uint2* __restrict__ bins) {
    __shared__ uint2 sorted[CHUNK];   // 48 KB bucket-sorted staging
    __shared__ int hist[NB];          // histogram -> inclusive scan (in place)
    __shared__ int lstart[NB];        // exclusive prefix (local run start)
    __shared__ int offs[NB];          // placement cursor
    __shared__ int gbase[NB];         // global base from bcnt atomic
    const int tid = threadIdx.x;
    const int ebase = blockIdx.x * CHUNK;
    const int nloc = (NE - ebase < CHUNK) ? (NE - ebase) : CHUNK;

    hist[tid] = 0;
    __syncthreads();

    // pass A: histogram destination buckets
    for (int k = 0; k < CPT; ++k) {
        int i = ebase + k * 256 + tid;
        if (i < NE) {
            uint_t b = (uint_t)col[i] / NPB;  // magic-mul div
            atomicAdd(&hist[b], 1);
        }
    }
    __syncthreads();

    // inclusive Hillis-Steele scan over 256 counters
    int v = hist[tid];
#pragma unroll
    for (int s = 1; s < NB; s <<= 1) {
        int t = (tid >= s) ? hist[tid - s] : 0;
        __syncthreads();
        hist[tid] += t;
        __syncthreads();
    }
    int excl = hist[tid] - v;
    lstart[tid] = excl;
    offs[tid] = excl;
    gbase[tid] = atomicAdd(&bcnt[tid * BSTRIDE], v);  // one cursor grab per bucket
    __syncthreads();

    // pass B: place records bucket-sorted into LDS (2nd read is L2-warm)
    for (int k = 0; k < CPT; ++k) {
        int i = ebase + k * 256 + tid;
        if (i < NE) {
            uint_t c = (uint_t)col[i];
            uint_t r = (uint_t)row[i];
            uint_t q = (uint_t)__float2int_rn(ew[i] * EW_SCALE);  // ew in [0,1)
            uint_t b = c / NPB;
            int pos = atomicAdd(&offs[b], 1);
            sorted[pos] = make_uint2((r << 15) | q, c);
        }
    }
    __syncthreads();

    // flush: consecutive i within a bucket -> consecutive global addresses
    for (int i = tid; i < nloc; i += 256) {
        uint2 rec = sorted[i];
        uint_t b = rec.y / NPB;
        int dst = gbase[b] + (i - lstart[b]);
        if (dst < BCAP) bins[(size_t)b * BCAP + dst] = rec;  // clamp defensive
    }
}

// Phase 2: one block per bucket; LDS-packed counter gives slot pos + sum(q)
// in ONE ds_add; slot writes land in a 100KB L2-resident window. Also emits
// cnt[] and dinv[].

__launch_bounds__(512)
__global__ void k_scatter(const int* __restrict__ bcnt, const uint2* __restrict__ bins,
                          int* __restrict__ cnt, uint_t* __restrict__ slots,
                          float* __restrict__ dinv) {
    // combo[lc]: bits 22..31 = edge count, bits 0..21 = sum of q (q<=32767,
    // deg<=42 -> qsum < 1.4M < 2^21, no field overflow on this graph).
    __shared__ int combo[NPB];
    const int b = blockIdx.x;
    const int tid = threadIdx.x;
    if (tid < NPB) combo[tid] = 0;
    __syncthreads();
    int n = bcnt[b * BSTRIDE];
    n = (n < BCAP) ? n : BCAP;
    const int base = b * NPB;
    const uint2* seg = bins + (size_t)b * BCAP;
    for (int i = tid; i < n; i += 512) {
        uint2 rec = seg[i];
        int lc = (int)rec.y - base;
        uint_t w = rec.x & 0x7fffu;
        uint_t old = (uint_t)atomicAdd(&combo[lc], (int)((1u << 22) | w));
        uint_t pos = old >> 22;
        if (pos < CAP) slots[rec.y * CAP + pos] = rec.x;
    }
    __syncthreads();
    if (tid < NPB) {
        int node = base + tid;
        if (node < NN) {
            uint_t v = (uint_t)combo[tid];
            int c = (int)(v >> 22);
            cnt[node] = (c < CAP) ? c : CAP;
            dinv[node] = rsqrtf(1.0f + (float)(v & 0x3fffffu) * EW_INV);
        }
    }
}

// ---------------- gather: one wave per destination node ----------------
// acc[c] = y[c] + sum_e ew_e * y[row_e]          (y rows are dinv-prescaled)
// RELU path (layer1): store y1 = dinv[c]*relu(dinv[c]*acc + b)   (bf16)
// else    (layer2): store g = dinv[c]*acc                         (fp32)

template <bool RELU, bool OUT_BF16>
__launch_bounds__(256)
__global__ void k_gather(const uint_t* __restrict__ src, const int* __restrict__ cnt,
                         const uint_t* __restrict__ slots, const float* __restrict__ dinv,
                         const float* __restrict__ bias, void* __restrict__ dst) {
    int wid = (blockIdx.x * blockDim.x + threadIdx.x) >> 6;  // node id
    int lane = threadIdx.x & 63;
    if (wid >= NN) return;
    float di = dinv[wid];
    uint_t u = src[wid * 64 + lane];
    float accx = bf_lo(u);
    float accy = bf_hi(u);
    int end = __builtin_amdgcn_readfirstlane(cnt[wid]);
    const uint_t* seg = slots + wid * CAP;
    for (int jj = 0; jj < end; jj += 8) {
        uint_t rp[8];
#pragma unroll
        for (int q = 0; q < 8; ++q) {
            int idx = (jj + q < end) ? (jj + q) : (end - 1);  // clamp: valid slot
            rp[q] = seg[idx];
        }
        uint_t sv[8];
#pragma unroll
        for (int q = 0; q < 8; ++q) {
            sv[q] = src[(rp[q] >> 15) * 64 + lane];
        }
#pragma unroll
        for (int q = 0; q < 8; ++q) {
            float p = (jj + q < end) ? (float)(rp[q] & 0x7fffu) * EW_INV : 0.0f;
            accx = fmaf(p, bf_lo(sv[q]), accx);
            accy = fmaf(p, bf_hi(sv[q]), accy);
        }
    }
    accx *= di;
    accy *= di;
    if (RELU) {
        float2 b = ((const float2*)bias)[lane];
        accx = fmaxf(accx + b.x, 0.0f) * di;  // prescale for next layer
        accy = fmaxf(accy + b.y, 0.0f) * di;
    }
    if (OUT_BF16) {
        ((uint_t*)dst)[wid * 64 + lane] =
            (uint_t)f2bf(accx) | ((uint_t)f2bf(accy) << 16);
    } else {
        ((float2*)dst)[wid * 64 + lane] = make_float2(accx, accy);
    }
}

// ------- GEMM: Y[n,:] = dinv[n] * (X[n,:] @ W), bf16 out (dinv-prescaled) -----
// 32-node x 128-col tile. X staged in LDS as float4 k-groups, pitch 33 float4s
// (odd 16B stride -> conflict-free b128 writes, no transpose). Per k-group:
// 8 ds_read_b128 (4 W rows + 4 x float4s, broadcast) feed 64 FMAs/thread.

__launch_bounds__(256)
__global__ void k_gemm_h0(const float* __restrict__ X, const float* __restrict__ W,
                          const float* __restrict__ dinv, uint_t* __restrict__ Y) {
    __shared__ float Ws[64 * 128];      // 32 KB, one k-half of W
    __shared__ float4 xs4[32 * 33];     // 16.9 KB: xs4[kg*33+n] = X[n][4kg..4kg+3]
    const int tid = threadIdx.x;
    const int node0 = blockIdx.x * 32;

    {
        const float4* X4 = (const float4*)X;
        for (int i = tid; i < 32 * 32; i += 256) {
            int n = i >> 5, kg = i & 31;   // coalesced global, conflict-free LDS
            xs4[kg * 33 + n] = X4[(node0 + n) * 32 + kg];
        }
    }

    const int jg = tid & 31, ng = tid >> 5;
    const int j0 = jg * 4, n0 = ng * 4;
    float acc[4][4];
#pragma unroll
    for (int a = 0; a < 4; ++a)
#pragma unroll
        for (int b = 0; b < 4; ++b) acc[a][b] = 0.0f;

    for (int half = 0; half < 2; ++half) {
        __syncthreads();  // xs4 ready / Ws no longer in use
        const float4* Wsrc = (const float4*)(W + half * 64 * 128);
        float4* Wd = (float4*)Ws;
        for (int i = tid; i < 64 * 32; i += 256) Wd[i] = Wsrc[i];
        __syncthreads();
#pragma unroll 4
        for (int kk4 = 0; kk4 < 16; ++kk4) {
            float4 wk[4], xa[4];
#pragma unroll
            for (int c = 0; c < 4; ++c)
                wk[c] = *(const float4*)&Ws[(kk4 * 4 + c) * 128 + j0];
#pragma unroll
            for (int a = 0; a < 4; ++a)
                xa[a] = xs4[(half * 16 + kk4) * 33 + n0 + a];
            float wv[4][4], xv[4][4];
#pragma unroll
            for (int c = 0; c < 4; ++c) {
                wv[c][0] = wk[c].x; wv[c][1] = wk[c].y;
                wv[c][2] = wk[c].z; wv[c][3] = wk[c].w;
            }
#pragma unroll
            for (int a = 0; a < 4; ++a) {
                xv[a][0] = xa[a].x; xv[a][1] = xa[a].y;
                xv[a][2] = xa[a].z; xv[a][3] = xa[a].w;
            }
#pragma unroll
            for (int c = 0; c < 4; ++c)
#pragma unroll
                for (int a = 0; a < 4; ++a)
#pragma unroll
                    for (int b = 0; b < 4; ++b)
                        acc[a][b] = fmaf(xv[a][c], wv[c][b], acc[a][b]);
        }
    }

#pragma unroll
    for (int a = 0; a < 4; ++a) {
        int node = node0 + n0 + a;
        float di = dinv[node];
        uint2 o;
        o.x = (uint_t)f2bf(acc[a][0] * di) | ((uint_t)f2bf(acc[a][1] * di) << 16);
        o.y = (uint_t)f2bf(acc[a][2] * di) | ((uint_t)f2bf(acc[a][3] * di) << 16);
        *(uint2*)&Y[node * 64 + (j0 >> 1)] = o;
    }
}

// ---------------- final GEMM: [mu|lv] = G @ [Wmu|Wlv] + [bmu|blv] -> d_out ----

__launch_bounds__(256)
__global__ void k_gemm_out(const float* __restrict__ G, const float* __restrict__ Wmu,
                           const float* __restrict__ Wlv, const float* __restrict__ bmu,
                           const float* __restrict__ blv, float* __restrict__ out) {
    __shared__ float Ws[64 * 128];
    __shared__ float4 xs4[32 * 33];
    const int tid = threadIdx.x;
    const int node0 = blockIdx.x * 32;

    {
        const float4* G4 = (const float4*)G;
        for (int i = tid; i < 32 * 32; i += 256) {
            int n = i >> 5, kg = i & 31;
            xs4[kg * 33 + n] = G4[(node0 + n) * 32 + kg];
        }
    }

    const int jg = tid & 31, ng = tid >> 5;
    const int j0 = jg * 4, n0 = ng * 4;
    float acc[4][4];
#pragma unroll
    for (int a = 0; a < 4; ++a)
#pragma unroll
        for (int b = 0; b < 4; ++b) acc[a][b] = 0.0f;

    for (int half = 0; half < 2; ++half) {
        __syncthreads();
        for (int i = tid; i < 64 * 32; i += 256) {
            int kk = i >> 5;
            int j = (i & 31) * 4;
            int k = half * 64 + kk;
            float4 v = (j < 64) ? *(const float4*)(Wmu + k * 64 + j)
                                : *(const float4*)(Wlv + k * 64 + (j - 64));
            ((float4*)Ws)[i] = v;
        }
        __syncthreads();
#pragma unroll 4
        for (int kk4 = 0; kk4 < 16; ++kk4) {
            float4 wk[4], xa[4];
#pragma unroll
            for (int c = 0; c < 4; ++c)
                wk[c] = *(const float4*)&Ws[(kk4 * 4 + c) * 128 + j0];
#pragma unroll
            for (int a = 0; a < 4; ++a)
                xa[a] = xs4[(half * 16 + kk4) * 33 + n0 + a];
            float wv[4][4], xv[4][4];
#pragma unroll
            for (int c = 0; c < 4; ++c) {
                wv[c][0] = wk[c].x; wv[c][1] = wk[c].y;
                wv[c][2] = wk[c].z; wv[c][3] = wk[c].w;
            }
#pragma unroll
            for (int a = 0; a < 4; ++a) {
                xv[a][0] = xa[a].x; xv[a][1] = xa[a].y;
                xv[a][2] = xa[a].z; xv[a][3] = xa[a].w;
            }
#pragma unroll
            for (int c = 0; c < 4; ++c)
#pragma unroll
                for (int a = 0; a < 4; ++a)
#pragma unroll
                    for (int b = 0; b < 4; ++b)
                        acc[a][b] = fmaf(xv[a][c], wv[c][b], acc[a][b]);
        }
    }

    float4 bb = (j0 < 64) ? *(const float4*)&bmu[j0] : *(const float4*)&blv[j0 - 64];
#pragma unroll
    for (int a = 0; a < 4; ++a) {
        int node = node0 + n0 + a;
        float4 v = make_float4(acc[a][0] + bb.x, acc[a][1] + bb.y,
                               acc[a][2] + bb.z, acc[a][3] + bb.w);
        if (j0 < 64)
            *(float4*)&out[node * 64 + j0] = v;
        else
            *(float4*)&out[OUT_HALF + node * 64 + (j0 - 64)] = v;
    }
}

// ---------------- launch ----------------

extern "C" void kernel_launch(void* const* d_in, const int* in_sizes, int n_in,
                              void* d_out, int out_size, void* d_ws, size_t ws_size,
                              hipStream_t stream) {
    const float* x   = (const float*)d_in[0];
    const int*   ei  = (const int*)d_in[1];   // [2, NE] int32 on device
    const float* ew  = (const float*)d_in[2];
    const float* W1  = (const float*)d_in[3];
    const float* b1  = (const float*)d_in[4];
    const float* Wmu = (const float*)d_in[5];
    const float* bmu = (const float*)d_in[6];
    const float* Wlv = (const float*)d_in[7];
    const float* blv = (const float*)d_in[8];
    const int* rowi = ei;        // sources
    const int* coli = ei + NE;   // destinations
    float* out = (float*)d_out;

    // workspace layout (4B elements). poolA holds y0 (bf16, 25.6MB) then is
    // overwritten by g (fp32, 51.2MB) during gather2 — y0 is dead by then.
    // During the BUILD phase (before k_gemm_h0 writes y0), poolA's first 17MB
    // is reused as bins (16.8MB) + bcnt (64KB) — both dead after k_scatter.
    int*    cnt   = (int*)d_ws;                  // NN ints, pad 100352
    float*  dinv  = (float*)(cnt + 100352);      // NN floats, pad 100352
    uint_t* slots = (uint_t*)(dinv + 100352);    // NN*CAP uints (25.6 MB)
    float*  poolA = (float*)(slots + NN * CAP);  // NN*128 floats (51.2 MB)
    uint_t* y0    = (uint_t*)poolA;              // NN*64 uints (bf16x2)
    float*  g     = poolA;                       // NN*128 floats
    uint_t* y1    = (uint_t*)(poolA + NN * DD);  // NN*64 uints (25.6 MB)
    uint2*  bins  = (uint2*)poolA;               // NB*BCAP uint2 (16.8 MB)
    int*    bcnt  = (int*)(poolA + NB * BCAP * 2);  // NB*BSTRIDE ints (64 KB)

    const int B = 256;
    // block-local counting sort -> contiguous per-bucket runs (full-line WB)
    k_zero<<<(NB * BSTRIDE + B - 1) / B, B, 0, stream>>>(bcnt);
    k_bin<<<(NE + CHUNK - 1) / CHUNK, B, 0, stream>>>(rowi, coli, ew, bcnt, bins);
    // per-bucket: slot placement via single packed LDS atomic; emits cnt+dinv
    k_scatter<<<NB, 512, 0, stream>>>(bcnt, bins, cnt, slots, dinv);
    // layer 1: y0 = dinv .* (x @ W1) -> bf16
    k_gemm_h0<<<NN / 32, B, 0, stream>>>(x, W1, dinv, y0);
    // y1 = dinv .* relu(dinv .* (y0[c] + sum ew*y0[r]) + b1) -> bf16
    k_gather<true, true><<<(NN * 64 + B - 1) / B, B, 0, stream>>>(
        y0, cnt, slots, dinv, b1, y1);
    // g = dinv .* (y1[c] + sum ew*y1[r]) -> fp32 (overwrites y0)
    k_gather<false, false><<<(NN * 64 + B - 1) / B, B, 0, stream>>>(
        y1, cnt, slots, dinv, b1, g);
    // [mu|logvar] = g @ [Wmu|Wlv] + bias -> d_out
    k_gemm_out<<<NN / 32, B, 0, stream>>>(g, Wmu, Wlv, bmu, blv, out);
}

// Round 3
// 395.853 us; speedup vs baseline: 1.1656x; 1.0039x over previous
//
#include <hip/hip_runtime.h>

#define NN 100000
#define NE 1600000
#define DD 128            // IN_DIM == HID == 128
#define OUT_HALF 6400000  // NN * 64
#define CAP 64            // slots per node (max degree on this fixed graph ~42)

// ---- binned-build parameters ----
#define NB 256            // coarse destination buckets (== k_bin block size)
#define NPB 391           // nodes per bucket (256*391 = 100096 >= NN)
#define BCAP 8192         // record capacity per bucket (E[n]=6250, +24 sigma)
#define BSTRIDE 64        // ints between bucket counters (256B apart)
#define CHUNK 6144        // edges per k_bin block (48KB LDS staging)
#define CPT 24            // CHUNK / 256

// ---- GEMM tile parameters (R2: 8x8 register blocking, LDS-BW fix) ----
#define GN 128            // nodes per block
#define XPITCH 144        // float4 pitch per k-group: 128 + 15 gap slots + pad

typedef unsigned int uint_t;

// round-to-nearest-even fp32 -> bf16 (as ushort)
__device__ __forceinline__ unsigned short f2bf(float f) {
    uint_t u = __float_as_uint(f);
    u = (u + 0x7fffu + ((u >> 16) & 1u)) >> 16;
    return (unsigned short)u;
}
__device__ __forceinline__ float bf_lo(uint_t u) { return __uint_as_float(u << 16); }
__device__ __forceinline__ float bf_hi(uint_t u) { return __uint_as_float(u & 0xffff0000u); }

#define EW_SCALE 32767.0f
#define EW_INV (1.0f / 32767.0f)

// ---------------- build: block-local counting sort -> binned CSR -------------
// R1 lesson: global bucket-appends do NOT write-combine — consecutive slots are
// claimed by different CUs on non-coherent XCD L2s, so every 8B record writes
// back its own 64B line (90MB observed). Fix: create contiguity INSIDE a block.

__global__ void k_zero(int* __restrict__ bcnt) {
    int i = blockIdx.x * blockDim.x + threadIdx.x;
    if (i < NB * BSTRIDE) bcnt[i] = 0;
}

__launch_bounds__(256)
__global__ void k_bin(const int* __restrict__ row, const int* __restrict__ col,
                      const float* __restrict__ ew, int* __restrict__ bcnt,
                      uint2* __restrict__ bins) {
    __shared__ uint2 sorted[CHUNK];   // 48 KB bucket-sorted staging
    __shared__ int hist[NB];          // histogram -> inclusive scan (in place)
    __shared__ int lstart[NB];        // exclusive prefix (local run start)
    __shared__ int offs[NB];          // placement cursor
    __shared__ int gbase[NB];         // global base from bcnt atomic
    const int tid = threadIdx.x;
    const int ebase = blockIdx.x * CHUNK;
    const int nloc = (NE - ebase < CHUNK) ? (NE - ebase) : CHUNK;

    hist[tid] = 0;
    __syncthreads();

    // pass A: histogram destination buckets
    for (int k = 0; k < CPT; ++k) {
        int i = ebase + k * 256 + tid;
        if (i < NE) {
            uint_t b = (uint_t)col[i] / NPB;  // magic-mul div
            atomicAdd(&hist[b], 1);
        }
    }
    __syncthreads();

    // inclusive Hillis-Steele scan over 256 counters
    int v = hist[tid];
#pragma unroll
    for (int s = 1; s < NB; s <<= 1) {
        int t = (tid >= s) ? hist[tid - s] : 0;
        __syncthreads();
        hist[tid] += t;
        __syncthreads();
    }
    int excl = hist[tid] - v;
    lstart[tid] = excl;
    offs[tid] = excl;
    gbase[tid] = atomicAdd(&bcnt[tid * BSTRIDE], v);  // one cursor grab per bucket
    __syncthreads();

    // pass B: place records bucket-sorted into LDS (2nd read is L2-warm)
    for (int k = 0; k < CPT; ++k) {
        int i = ebase + k * 256 + tid;
        if (i < NE) {
            uint_t c = (uint_t)col[i];
            uint_t r = (uint_t)row[i];
            uint_t q = (uint_t)__float2int_rn(ew[i] * EW_SCALE);  // ew in [0,1)
            uint_t b = c / NPB;
            int pos = atomicAdd(&offs[b], 1);
            sorted[pos] = make_uint2((r << 15) | q, c);
        }
    }
    __syncthreads();

    // flush: consecutive i within a bucket -> consecutive global addresses
    for (int i = tid; i < nloc; i += 256) {
        uint2 rec = sorted[i];
        uint_t b = rec.y / NPB;
        int dst = gbase[b] + (i - lstart[b]);
        if (dst < BCAP) bins[(size_t)b * BCAP + dst] = rec;  // clamp defensive
    }
}

// Phase 2: one block per bucket; LDS-packed counter gives slot pos + sum(q)
// in ONE ds_add; slot writes land in a 100KB L2-resident window. Also emits
// cnt[] and dinv[].

__launch_bounds__(512)
__global__ void k_scatter(const int* __restrict__ bcnt, const uint2* __restrict__ bins,
                          int* __restrict__ cnt, uint_t* __restrict__ slots,
                          float* __restrict__ dinv) {
    // combo[lc]: bits 22..31 = edge count, bits 0..21 = sum of q (q<=32767,
    // deg<=42 -> qsum < 1.4M < 2^21, no field overflow on this graph).
    __shared__ int combo[NPB];
    const int b = blockIdx.x;
    const int tid = threadIdx.x;
    if (tid < NPB) combo[tid] = 0;
    __syncthreads();
    int n = bcnt[b * BSTRIDE];
    n = (n < BCAP) ? n : BCAP;
    const int base = b * NPB;
    const uint2* seg = bins + (size_t)b * BCAP;
    for (int i = tid; i < n; i += 512) {
        uint2 rec = seg[i];
        int lc = (int)rec.y - base;
        uint_t w = rec.x & 0x7fffu;
        uint_t old = (uint_t)atomicAdd(&combo[lc], (int)((1u << 22) | w));
        uint_t pos = old >> 22;
        if (pos < CAP) slots[rec.y * CAP + pos] = rec.x;
    }
    __syncthreads();
    if (tid < NPB) {
        int node = base + tid;
        if (node < NN) {
            uint_t v = (uint_t)combo[tid];
            int c = (int)(v >> 22);
            cnt[node] = (c < CAP) ? c : CAP;
            dinv[node] = rsqrtf(1.0f + (float)(v & 0x3fffffu) * EW_INV);
        }
    }
}

// ---------------- gather: one wave per destination node ----------------

template <bool RELU, bool OUT_BF16>
__launch_bounds__(256)
__global__ void k_gather(const uint_t* __restrict__ src, const int* __restrict__ cnt,
                         const uint_t* __restrict__ slots, const float* __restrict__ dinv,
                         const float* __restrict__ bias, void* __restrict__ dst) {
    int wid = (blockIdx.x * blockDim.x + threadIdx.x) >> 6;  // node id
    int lane = threadIdx.x & 63;
    if (wid >= NN) return;
    float di = dinv[wid];
    uint_t u = src[wid * 64 + lane];
    float accx = bf_lo(u);
    float accy = bf_hi(u);
    int end = __builtin_amdgcn_readfirstlane(cnt[wid]);
    const uint_t* seg = slots + wid * CAP;
    for (int jj = 0; jj < end; jj += 8) {
        uint_t rp[8];
#pragma unroll
        for (int q = 0; q < 8; ++q) {
            int idx = (jj + q < end) ? (jj + q) : (end - 1);  // clamp: valid slot
            rp[q] = seg[idx];
        }
        uint_t sv[8];
#pragma unroll
        for (int q = 0; q < 8; ++q) {
            sv[q] = src[(rp[q] >> 15) * 64 + lane];
        }
#pragma unroll
        for (int q = 0; q < 8; ++q) {
            float p = (jj + q < end) ? (float)(rp[q] & 0x7fffu) * EW_INV : 0.0f;
            accx = fmaf(p, bf_lo(sv[q]), accx);
            accy = fmaf(p, bf_hi(sv[q]), accy);
        }
    }
    accx *= di;
    accy *= di;
    if (RELU) {
        float2 b = ((const float2*)bias)[lane];
        accx = fmaxf(accx + b.x, 0.0f) * di;  // prescale for next layer
        accy = fmaxf(accy + b.y, 0.0f) * di;
    }
    if (OUT_BF16) {
        ((uint_t*)dst)[wid * 64 + lane] =
            (uint_t)f2bf(accx) | ((uint_t)f2bf(accy) << 16);
    } else {
        ((float2*)dst)[wid * 64 + lane] = make_float2(accx, accy);
    }
}

// ------- GEMMs: 128-node x 128-col tile, 8x8 register blocking ---------------
// R2 lesson: the 4x4 tile was LDS-BW-bound (2 B/FMA -> 63us of ds_read time).
// 8x8 halves LDS bytes/FMA. Per thread: cols {jg*4..+3} u {64+jg*4..+3}
// (16B-stride W reads -> 2-way bank aliasing = free), nodes ng*8..+7.
// X tile stored kg-major with slot(n)=n+(n>>3) so the 4 broadcast node-group
// addresses per wave hit distinct bank quads. K processed in 2 halves of 64.

__launch_bounds__(256, 2)
__global__ void k_gemm_h0(const float* __restrict__ X, const float* __restrict__ W,
                          const float* __restrict__ dinv, uint_t* __restrict__ Y) {
    __shared__ float Ws[64 * 128];        // 32 KB: one k-half of W
    __shared__ float4 xs4[16 * XPITCH];   // 36 KB: xs4[kg][slot(n)] = X[n][4kg..]
    const int tid = threadIdx.x;
    const int node0 = blockIdx.x * GN;
    const int jg = tid & 15, ng = tid >> 4;
    const int jlo = jg * 4, jhi = 64 + jg * 4;
    const int ng9 = ng * 9;               // slot(ng*8) = ng*9

    float acc[8][8];
#pragma unroll
    for (int a = 0; a < 8; ++a)
#pragma unroll
        for (int b = 0; b < 8; ++b) acc[a][b] = 0.0f;

    const float4* X4 = (const float4*)X;
    for (int half = 0; half < 2; ++half) {
        __syncthreads();  // buffers free
        {
            const float4* Wsrc = (const float4*)(W + half * 64 * 128);
            float4* Wd = (float4*)Ws;
            for (int i = tid; i < 64 * 32; i += 256) Wd[i] = Wsrc[i];
            for (int i = tid; i < GN * 16; i += 256) {
                int n = i >> 4, kg = i & 15;
                int ne = node0 + n;
                if (ne >= NN) ne = NN - 1;       // clamp: harmless duplicate
                xs4[kg * XPITCH + n + (n >> 3)] = X4[ne * 32 + half * 16 + kg];
            }
        }
        __syncthreads();
#pragma unroll 4
        for (int kk4 = 0; kk4 < 16; ++kk4) {
            float4 xa[8];
#pragma unroll
            for (int a = 0; a < 8; ++a) xa[a] = xs4[kk4 * XPITCH + ng9 + a];
#pragma unroll
            for (int c = 0; c < 4; ++c) {
                const int kk = kk4 * 4 + c;
                float4 wlo = *(const float4*)&Ws[kk * 128 + jlo];
                float4 whi = *(const float4*)&Ws[kk * 128 + jhi];
#pragma unroll
                for (int a = 0; a < 8; ++a) {
                    float xk = (c == 0) ? xa[a].x : (c == 1) ? xa[a].y
                             : (c == 2) ? xa[a].z : xa[a].w;
                    acc[a][0] = fmaf(xk, wlo.x, acc[a][0]);
                    acc[a][1] = fmaf(xk, wlo.y, acc[a][1]);
                    acc[a][2] = fmaf(xk, wlo.z, acc[a][2]);
                    acc[a][3] = fmaf(xk, wlo.w, acc[a][3]);
                    acc[a][4] = fmaf(xk, whi.x, acc[a][4]);
                    acc[a][5] = fmaf(xk, whi.y, acc[a][5]);
                    acc[a][6] = fmaf(xk, whi.z, acc[a][6]);
                    acc[a][7] = fmaf(xk, whi.w, acc[a][7]);
                }
            }
        }
    }

#pragma unroll
    for (int a = 0; a < 8; ++a) {
        int node = node0 + ng * 8 + a;
        if (node < NN) {
            float di = dinv[node];
            uint2 lo, hi;
            lo.x = (uint_t)f2bf(acc[a][0] * di) | ((uint_t)f2bf(acc[a][1] * di) << 16);
            lo.y = (uint_t)f2bf(acc[a][2] * di) | ((uint_t)f2bf(acc[a][3] * di) << 16);
            hi.x = (uint_t)f2bf(acc[a][4] * di) | ((uint_t)f2bf(acc[a][5] * di) << 16);
            hi.y = (uint_t)f2bf(acc[a][6] * di) | ((uint_t)f2bf(acc[a][7] * di) << 16);
            *(uint2*)&Y[node * 64 + jg * 2] = lo;       // cols jlo..jlo+3
            *(uint2*)&Y[node * 64 + 32 + jg * 2] = hi;  // cols jhi..jhi+3
        }
    }
}

// final GEMM: [mu|lv] = G @ [Wmu|Wlv] + [bmu|blv] -> d_out.
// Low col-quad (jlo<64) is always Wmu/mu; high quad always Wlv/logvar.

__launch_bounds__(256, 2)
__global__ void k_gemm_out(const float* __restrict__ G, const float* __restrict__ Wmu,
                           const float* __restrict__ Wlv, const float* __restrict__ bmu,
                           const float* __restrict__ blv, float* __restrict__ out) {
    __shared__ float Ws[64 * 128];
    __shared__ float4 xs4[16 * XPITCH];
    const int tid = threadIdx.x;
    const int node0 = blockIdx.x * GN;
    const int jg = tid & 15, ng = tid >> 4;
    const int jlo = jg * 4, jhi = 64 + jg * 4;
    const int ng9 = ng * 9;

    float acc[8][8];
#pragma unroll
    for (int a = 0; a < 8; ++a)
#pragma unroll
        for (int b = 0; b < 8; ++b) acc[a][b] = 0.0f;

    const float4* G4 = (const float4*)G;
    for (int half = 0; half < 2; ++half) {
        __syncthreads();
        {
            const float4* Wm4 = (const float4*)(Wmu + half * 64 * 64);
            const float4* Wl4 = (const float4*)(Wlv + half * 64 * 64);
            float4* Wd = (float4*)Ws;
            for (int i = tid; i < 64 * 32; i += 256) {
                int kk = i >> 5, cj = i & 31;
                Wd[i] = (cj < 16) ? Wm4[kk * 16 + cj] : Wl4[kk * 16 + (cj - 16)];
            }
            for (int i = tid; i < GN * 16; i += 256) {
                int n = i >> 4, kg = i & 15;
                int ne = node0 + n;
                if (ne >= NN) ne = NN - 1;
                xs4[kg * XPITCH + n + (n >> 3)] = G4[ne * 32 + half * 16 + kg];
            }
        }
        __syncthreads();
#pragma unroll 4
        for (int kk4 = 0; kk4 < 16; ++kk4) {
            float4 xa[8];
#pragma unroll
            for (int a = 0; a < 8; ++a) xa[a] = xs4[kk4 * XPITCH + ng9 + a];
#pragma unroll
            for (int c = 0; c < 4; ++c) {
                const int kk = kk4 * 4 + c;
                float4 wlo = *(const float4*)&Ws[kk * 128 + jlo];
                float4 whi = *(const float4*)&Ws[kk * 128 + jhi];
#pragma unroll
                for (int a = 0; a < 8; ++a) {
                    float xk = (c == 0) ? xa[a].x : (c == 1) ? xa[a].y
                             : (c == 2) ? xa[a].z : xa[a].w;
                    acc[a][0] = fmaf(xk, wlo.x, acc[a][0]);
                    acc[a][1] = fmaf(xk, wlo.y, acc[a][1]);
                    acc[a][2] = fmaf(xk, wlo.z, acc[a][2]);
                    acc[a][3] = fmaf(xk, wlo.w, acc[a][3]);
                    acc[a][4] = fmaf(xk, whi.x, acc[a][4]);
                    acc[a][5] = fmaf(xk, whi.y, acc[a][5]);
                    acc[a][6] = fmaf(xk, whi.z, acc[a][6]);
                    acc[a][7] = fmaf(xk, whi.w, acc[a][7]);
                }
            }
        }
    }

    float4 bm = *(const float4*)&bmu[jlo];
    float4 bl = *(const float4*)&blv[jlo];
#pragma unroll
    for (int a = 0; a < 8; ++a) {
        int node = node0 + ng * 8 + a;
        if (node < NN) {
            float4 vmu = make_float4(acc[a][0] + bm.x, acc[a][1] + bm.y,
                                     acc[a][2] + bm.z, acc[a][3] + bm.w);
            float4 vlv = make_float4(acc[a][4] + bl.x, acc[a][5] + bl.y,
                                     acc[a][6] + bl.z, acc[a][7] + bl.w);
            *(float4*)&out[node * 64 + jlo] = vmu;
            *(float4*)&out[OUT_HALF + node * 64 + jlo] = vlv;
        }
    }
}

// ---------------- launch ----------------

extern "C" void kernel_launch(void* const* d_in, const int* in_sizes, int n_in,
                              void* d_out, int out_size, void* d_ws, size_t ws_size,
                              hipStream_t stream) {
    const float* x   = (const float*)d_in[0];
    const int*   ei  = (const int*)d_in[1];   // [2, NE] int32 on device
    const float* ew  = (const float*)d_in[2];
    const float* W1  = (const float*)d_in[3];
    const float* b1  = (const float*)d_in[4];
    const float* Wmu = (const float*)d_in[5];
    const float* bmu = (const float*)d_in[6];
    const float* Wlv = (const float*)d_in[7];
    const float* blv = (const float*)d_in[8];
    const int* rowi = ei;        // sources
    const int* coli = ei + NE;   // destinations
    float* out = (float*)d_out;

    // workspace layout (4B elements). poolA holds y0 (bf16, 25.6MB) then is
    // overwritten by g (fp32, 51.2MB) during gather2 — y0 is dead by then.
    // During the BUILD phase (before k_gemm_h0 writes y0), poolA's first 17MB
    // is reused as bins (16.8MB) + bcnt (64KB) — both dead after k_scatter.
    int*    cnt   = (int*)d_ws;                  // NN ints, pad 100352
    float*  dinv  = (float*)(cnt + 100352);      // NN floats, pad 100352
    uint_t* slots = (uint_t*)(dinv + 100352);    // NN*CAP uints (25.6 MB)
    float*  poolA = (float*)(slots + NN * CAP);  // NN*128 floats (51.2 MB)
    uint_t* y0    = (uint_t*)poolA;              // NN*64 uints (bf16x2)
    float*  g     = poolA;                       // NN*128 floats
    uint_t* y1    = (uint_t*)(poolA + NN * DD);  // NN*64 uints (25.6 MB)
    uint2*  bins  = (uint2*)poolA;               // NB*BCAP uint2 (16.8 MB)
    int*    bcnt  = (int*)(poolA + NB * BCAP * 2);  // NB*BSTRIDE ints (64 KB)

    const int B = 256;
    const int GGRID = (NN + GN - 1) / GN;  // 782
    // block-local counting sort -> contiguous per-bucket runs (full-line WB)
    k_zero<<<(NB * BSTRIDE + B - 1) / B, B, 0, stream>>>(bcnt);
    k_bin<<<(NE + CHUNK - 1) / CHUNK, B, 0, stream>>>(rowi, coli, ew, bcnt, bins);
    // per-bucket: slot placement via single packed LDS atomic; emits cnt+dinv
    k_scatter<<<NB, 512, 0, stream>>>(bcnt, bins, cnt, slots, dinv);
    // layer 1: y0 = dinv .* (x @ W1) -> bf16
    k_gemm_h0<<<GGRID, B, 0, stream>>>(x, W1, dinv, y0);
    // y1 = dinv .* relu(dinv .* (y0[c] + sum ew*y0[r]) + b1) -> bf16
    k_gather<true, true><<<(NN * 64 + B - 1) / B, B, 0, stream>>>(
        y0, cnt, slots, dinv, b1, y1);
    // g = dinv .* (y1[c] + sum ew*y1[r]) -> fp32 (overwrites y0)
    k_gather<false, false><<<(NN * 64 + B - 1) / B, B, 0, stream>>>(
        y1, cnt, slots, dinv, b1, g);
    // [mu|logvar] = g @ [Wmu|Wlv] + bias -> d_out
    k_gemm_out<<<GGRID, B, 0, stream>>>(g, Wmu, Wlv, bmu, blv, out);
}